// Round 3
// baseline (111.030 us; speedup 1.0000x reference)
//
#include <hip/hip_runtime.h>

#define B_TOTAL 524288
#define HID 128
#define ROWS 4
#define BLK 256
#define NBLK (B_TOTAL / ROWS / BLK)   // 512

static __device__ __forceinline__ float fast_exp2(float x) {
    float r;
    asm("v_exp_f32 %0, %1" : "=v"(r) : "v"(x));
    return r;
}

// Pack per-hidden-unit weights contiguously: [W1col*2log2e (5), b1*2log2e, W2row (2)]
// so the hidden dot-product directly yields log2(exp(2a)) for the tanh identity.
__global__ void pack_w(const float* __restrict__ W1, const float* __restrict__ b1,
                       const float* __restrict__ W2, float* __restrict__ wp) {
    const int j = threadIdx.x;
    if (j < HID) {
        const float s = 2.8853900817779268f; // 2*log2(e)
        wp[j * 8 + 0] = W1[0 * HID + j] * s;
        wp[j * 8 + 1] = W1[1 * HID + j] * s;
        wp[j * 8 + 2] = W1[2 * HID + j] * s;
        wp[j * 8 + 3] = W1[3 * HID + j] * s;
        wp[j * 8 + 4] = W1[4 * HID + j] * s;
        wp[j * 8 + 5] = b1[j] * s;
        wp[j * 8 + 6] = W2[j * 2 + 0];
        wp[j * 8 + 7] = W2[j * 2 + 1];
    }
}

__global__ __launch_bounds__(BLK, 2) void ode_kernel(
    const float* __restrict__ t,
    const float* __restrict__ u,
    const float* __restrict__ p,
    const float* __restrict__ wp,
    const float* __restrict__ b2,
    float* __restrict__ out)
{
    const int g = blockIdx.x * BLK + threadIdx.x;

    // ---- 4 adjacent rows per thread: u block = 160B = 10 float4 (16B aligned) ----
    float ub[ROWS * 10];
    const float4* u4 = reinterpret_cast<const float4*>(u + (size_t)g * (ROWS * 10));
#pragma unroll
    for (int i = 0; i < 10; ++i) reinterpret_cast<float4*>(ub)[i] = u4[i];

    const float4 tv4 = *reinterpret_cast<const float4*>(t + (size_t)g * ROWS);
    const float tv[ROWS] = {tv4.x, tv4.y, tv4.z, tv4.w};

    // ---- MLP: weights via uniform-address loads (SMEM/L1 broadcast, zero LDS) ----
    const float b20 = b2[0], b21 = b2[1];
    float z0[ROWS], z1[ROWS];
#pragma unroll
    for (int r = 0; r < ROWS; ++r) { z0[r] = b20; z1[r] = b21; }

    const float4* wp4 = reinterpret_cast<const float4*>(wp);
#pragma unroll 4
    for (int j = 0; j < HID; ++j) {
        const float4 wa = wp4[2 * j];
        const float4 wb = wp4[2 * j + 1];
#pragma unroll
        for (int r = 0; r < ROWS; ++r) {
            float y = wb.y;                              // b1 * 2log2e
            y = fmaf(ub[r * 10 + 4], wa.x, y);           // Vlv
            y = fmaf(ub[r * 10 + 5], wa.y, y);           // Vao
            y = fmaf(ub[r * 10 + 6], wa.z, y);           // Vvc
            y = fmaf(ub[r * 10 + 7], wa.w, y);           // Vrv
            y = fmaf(ub[r * 10 + 8], wb.x, y);           // Vpa
            const float e2 = fast_exp2(y);               // = exp(2a)
            const float th = 1.0f - 2.0f * __builtin_amdgcn_rcpf(e2 + 1.0f);
            z0[r] = fmaf(th, wb.z, z0[r]);
            z1[r] = fmaf(th, wb.w, z1[r]);
        }
    }

    // ---- uniform p scalars (s_loads) ----
    const float Elvf = p[0],  Eao = p[1],   Evc = p[2],   Ervf = p[3];
    const float Epa  = p[4],  Epu = p[5];
    const float Rmt  = p[6],  Rav = p[7],   Rsys = p[8],  Rtc = p[9];
    const float Rpv  = p[10], Rpul = p[11];
    const float Lmt  = p[12], Lav = p[13],  Ltc = p[14],  Lpv = p[15];
    const float Vdlvf = p[16], Vdao = p[17], Vdvc = p[18], Vdrvf = p[19];
    const float Vdpa  = p[20], Vdpu = p[21];
    const float P0lvf = p[22], P0rvf = p[23];
    const float lamlvf = p[24], lamrvf = p[25];
    const float V0lvf = p[27], V0rvf = p[28];
    const float Pth   = p[36];

    const float L2E = 1.4426950408889634f;
    const float inv_Rsys = __builtin_amdgcn_rcpf(Rsys);
    const float inv_Rpul = __builtin_amdgcn_rcpf(Rpul);
    const float inv_Lmt  = __builtin_amdgcn_rcpf(Lmt);
    const float inv_Lav  = __builtin_amdgcn_rcpf(Lav);
    const float inv_Ltc  = __builtin_amdgcn_rcpf(Ltc);
    const float inv_Lpv  = __builtin_amdgcn_rcpf(Lpv);
    const float laml_l2e = lamlvf * L2E;
    const float lamr_l2e = lamrvf * L2E;
    const float CLAMP2 = 88.0f * L2E;   // exp(min(x,88)) == exp2(min(x*l2e, 88*l2e))

    float du[ROWS * 10];
#pragma unroll
    for (int r = 0; r < ROWS; ++r) {
        const float Qmt = ub[r * 10 + 0], Qav = ub[r * 10 + 1];
        const float Qtc = ub[r * 10 + 2], Qpv = ub[r * 10 + 3];
        const float Vlv = ub[r * 10 + 4], Vao = ub[r * 10 + 5];
        const float Vvc = ub[r * 10 + 6], Vrv = ub[r * 10 + 7];
        const float Vpa = ub[r * 10 + 8], Vpu = ub[r * 10 + 9];
        const float Pperi = z0[r], Vspt = z1[r];

        // e = exp(-80*(mod(t,0.75)-0.375)^2), t in [0,1)
        const float m  = (tv[r] >= 0.75f) ? (tv[r] - 0.75f) : tv[r];
        const float dd = m - 0.375f;
        const float e  = fast_exp2(dd * dd * (-80.0f * L2E));

        const float Vlvf = Vlv - Vspt;
        const float Vrvf = Vrv + Vspt;
        const float exp_lv = fast_exp2(fminf(laml_l2e * (Vlvf - V0lvf), CLAMP2));
        const float exp_rv = fast_exp2(fminf(lamr_l2e * (Vrvf - V0rvf), CLAMP2));
        const float ome = 1.0f - e;
        const float Plvf = e * Elvf * (Vlvf - Vdlvf) + ome * P0lvf * (exp_lv - 1.0f);
        const float Prvf = e * Ervf * (Vrvf - Vdrvf) + ome * P0rvf * (exp_rv - 1.0f);
        const float Plv = Plvf + Pperi;
        const float Prv = Prvf + Pperi;
        const float Pao = Eao * (Vao - Vdao);
        const float Pvc = Evc * (Vvc - Vdvc);
        const float Ppa = fmaf(Epa, Vpa - Vdpa, Pth);
        const float Ppu = fmaf(Epu, Vpu - Vdpu, Pth);
        const float Qsys = (Pao - Pvc) * inv_Rsys;
        const float Qpul = (Ppa - Ppu) * inv_Rpul;

        du[r * 10 + 0] = ((Ppu - Plv > 0.0f) || (Qmt > 0.0f)) ? (Ppu - Plv - Qmt * Rmt) * inv_Lmt : 0.0f;
        du[r * 10 + 1] = ((Plv - Pao > 0.0f) || (Qav > 0.0f)) ? (Plv - Pao - Qav * Rav) * inv_Lav : 0.0f;
        du[r * 10 + 2] = ((Pvc - Prv > 0.0f) || (Qtc > 0.0f)) ? (Pvc - Prv - Qtc * Rtc) * inv_Ltc : 0.0f;
        du[r * 10 + 3] = ((Prv - Ppa > 0.0f) || (Qpv > 0.0f)) ? (Prv - Ppa - Qpv * Rpv) * inv_Lpv : 0.0f;

        const float Qmt_c = fmaxf(Qmt, 0.0f);
        const float Qav_c = fmaxf(Qav, 0.0f);
        const float Qtc_c = fmaxf(Qtc, 0.0f);
        const float Qpv_c = fmaxf(Qpv, 0.0f);
        du[r * 10 + 4] = Qmt_c - Qav_c;
        du[r * 10 + 5] = Qav_c - Qsys;
        du[r * 10 + 6] = Qsys - Qtc_c;
        du[r * 10 + 7] = Qtc_c - Qpv_c;
        du[r * 10 + 8] = Qpv_c - Qpul;
        du[r * 10 + 9] = Qpul - Qmt_c;
    }

    float4* o4 = reinterpret_cast<float4*>(out + (size_t)g * (ROWS * 10));
#pragma unroll
    for (int i = 0; i < 10; ++i) o4[i] = reinterpret_cast<const float4*>(du)[i];
}

extern "C" void kernel_launch(void* const* d_in, const int* in_sizes, int n_in,
                              void* d_out, int out_size, void* d_ws, size_t ws_size,
                              hipStream_t stream) {
    const float* t  = (const float*)d_in[0];
    const float* u  = (const float*)d_in[1];
    const float* p  = (const float*)d_in[2];
    const float* W1 = (const float*)d_in[3];
    const float* b1 = (const float*)d_in[4];
    const float* W2 = (const float*)d_in[5];
    const float* b2 = (const float*)d_in[6];
    float* out = (float*)d_out;
    float* wp  = (float*)d_ws;   // 4KB packed weights

    pack_w<<<1, HID, 0, stream>>>(W1, b1, W2, wp);
    ode_kernel<<<NBLK, BLK, 0, stream>>>(t, u, p, wp, b2, out);
}

// Round 5
// 106.864 us; speedup vs baseline: 1.0390x; 1.0390x over previous
//
#include <hip/hip_runtime.h>

#define B_TOTAL 524288
#define HID 128
#define ROWS 4
#define BLK 256
#define NBLK (B_TOTAL / ROWS / BLK)   // 512 blocks = 2 per CU

typedef float v2f __attribute__((ext_vector_type(2)));

static __device__ __forceinline__ float fast_exp2(float x) {
    float r;
    asm("v_exp_f32 %0, %1" : "=v"(r) : "v"(x));
    return r;
}
static __device__ __forceinline__ v2f splat2(float x) { v2f r; r.x = x; r.y = x; return r; }

#if __has_builtin(__builtin_elementwise_fma)
static __device__ __forceinline__ v2f fma2(v2f a, v2f b, v2f c) {
    return __builtin_elementwise_fma(a, b, c);   // -> v_pk_fma_f32
}
#else
static __device__ __forceinline__ v2f fma2(v2f a, v2f b, v2f c) {
    v2f r; r.x = fmaf(a.x, b.x, c.x); r.y = fmaf(a.y, b.y, c.y); return r;
}
#endif

__global__ __launch_bounds__(BLK, 2) void ode_kernel(
    const float* __restrict__ t,
    const float* __restrict__ u,
    const float* __restrict__ p,
    const float* __restrict__ W1,
    const float* __restrict__ b1,
    const float* __restrict__ W2,
    const float* __restrict__ b2,
    float* __restrict__ out)
{
    const int g = blockIdx.x * BLK + threadIdx.x;

    // ---- 4 adjacent rows per thread: u block = 160B = 10 float4 ----
    float ub[ROWS * 10];
    const float4* u4 = reinterpret_cast<const float4*>(u + (size_t)g * (ROWS * 10));
#pragma unroll
    for (int i = 0; i < 10; ++i) reinterpret_cast<float4*>(ub)[i] = u4[i];

    const float4 tv4 = *reinterpret_cast<const float4*>(t + (size_t)g * ROWS);
    const float tv[ROWS] = {tv4.x, tv4.y, tv4.z, tv4.w};

    // ---- pair-pack MLP inputs: vin[pr][k] = {row 2pr, row 2pr+1} ----
    v2f vin[2][5];
#pragma unroll
    for (int pr = 0; pr < 2; ++pr)
#pragma unroll
        for (int k = 0; k < 5; ++k) {
            v2f v; v.x = ub[(2 * pr) * 10 + 4 + k]; v.y = ub[(2 * pr + 1) * 10 + 4 + k];
            vin[pr][k] = v;
        }

    const float S2L2E = 2.8853900817779268f;  // 2*log2(e): exp(2a) == exp2(S2L2E*a)
    const v2f s2v = splat2(S2L2E);

    v2f z0p[2], z1p[2];
    z0p[0] = z0p[1] = splat2(b2[0]);
    z1p[0] = z1p[1] = splat2(b2[1]);

    // ---- MLP j-loop: weights via uniform-address (scalar/const-cache) loads ----
#pragma unroll 2
    for (int jg = 0; jg < HID; jg += 4) {
        float w1c[4][5];
#pragma unroll
        for (int k = 0; k < 5; ++k) {
            const float4 w4 = *reinterpret_cast<const float4*>(W1 + k * HID + jg);
            w1c[0][k] = w4.x; w1c[1][k] = w4.y; w1c[2][k] = w4.z; w1c[3][k] = w4.w;
        }
        const float4 b14 = *reinterpret_cast<const float4*>(b1 + jg);
        const float bb[4] = {b14.x, b14.y, b14.z, b14.w};
        const float4 w2a = *reinterpret_cast<const float4*>(W2 + 2 * jg);
        const float4 w2b = *reinterpret_cast<const float4*>(W2 + 2 * jg + 4);
        const float w20[4] = {w2a.x, w2a.z, w2b.x, w2b.z};
        const float w21[4] = {w2a.y, w2a.w, w2b.y, w2b.w};

#pragma unroll
        for (int jj = 0; jj < 4; ++jj) {
#pragma unroll
            for (int pr = 0; pr < 2; ++pr) {
                v2f y = splat2(bb[jj]);
                y = fma2(vin[pr][0], splat2(w1c[jj][0]), y);
                y = fma2(vin[pr][1], splat2(w1c[jj][1]), y);
                y = fma2(vin[pr][2], splat2(w1c[jj][2]), y);
                y = fma2(vin[pr][3], splat2(w1c[jj][3]), y);
                y = fma2(vin[pr][4], splat2(w1c[jj][4]), y);
                y = y * s2v;                       // log2(exp(2a))
                v2f e2; e2.x = fast_exp2(y.x); e2.y = fast_exp2(y.y);
                e2 = e2 + splat2(1.0f);
                v2f rc; rc.x = __builtin_amdgcn_rcpf(e2.x); rc.y = __builtin_amdgcn_rcpf(e2.y);
                const v2f th = fma2(rc, splat2(-2.0f), splat2(1.0f));  // tanh(a)
                z0p[pr] = fma2(th, splat2(w20[jj]), z0p[pr]);
                z1p[pr] = fma2(th, splat2(w21[jj]), z1p[pr]);
            }
        }
    }

    const float z0[ROWS] = {z0p[0].x, z0p[0].y, z0p[1].x, z0p[1].y};
    const float z1[ROWS] = {z1p[0].x, z1p[0].y, z1p[1].x, z1p[1].y};

    // ---- uniform p scalars ----
    const float Elvf = p[0],  Eao = p[1],   Evc = p[2],   Ervf = p[3];
    const float Epa  = p[4],  Epu = p[5];
    const float Rmt  = p[6],  Rav = p[7],   Rsys = p[8],  Rtc = p[9];
    const float Rpv  = p[10], Rpul = p[11];
    const float Lmt  = p[12], Lav = p[13],  Ltc = p[14],  Lpv = p[15];
    const float Vdlvf = p[16], Vdao = p[17], Vdvc = p[18], Vdrvf = p[19];
    const float Vdpa  = p[20], Vdpu = p[21];
    const float P0lvf = p[22], P0rvf = p[23];
    const float lamlvf = p[24], lamrvf = p[25];
    const float V0lvf = p[27], V0rvf = p[28];
    const float Pth   = p[36];

    const float L2E = 1.4426950408889634f;
    const float inv_Rsys = __builtin_amdgcn_rcpf(Rsys);
    const float inv_Rpul = __builtin_amdgcn_rcpf(Rpul);
    const float inv_Lmt  = __builtin_amdgcn_rcpf(Lmt);
    const float inv_Lav  = __builtin_amdgcn_rcpf(Lav);
    const float inv_Ltc  = __builtin_amdgcn_rcpf(Ltc);
    const float inv_Lpv  = __builtin_amdgcn_rcpf(Lpv);
    const float laml_l2e = lamlvf * L2E;
    const float lamr_l2e = lamrvf * L2E;
    const float CLAMP2 = 88.0f * L2E;

    float du[ROWS * 10];
#pragma unroll
    for (int r = 0; r < ROWS; ++r) {
        const float Qmt = ub[r * 10 + 0], Qav = ub[r * 10 + 1];
        const float Qtc = ub[r * 10 + 2], Qpv = ub[r * 10 + 3];
        const float Vlv = ub[r * 10 + 4], Vao = ub[r * 10 + 5];
        const float Vvc = ub[r * 10 + 6], Vrv = ub[r * 10 + 7];
        const float Vpa = ub[r * 10 + 8], Vpu = ub[r * 10 + 9];
        const float Pperi = z0[r], Vspt = z1[r];

        const float m  = (tv[r] >= 0.75f) ? (tv[r] - 0.75f) : tv[r];
        const float dd = m - 0.375f;
        const float e  = fast_exp2(dd * dd * (-80.0f * L2E));

        const float Vlvf = Vlv - Vspt;
        const float Vrvf = Vrv + Vspt;
        const float exp_lv = fast_exp2(fminf(laml_l2e * (Vlvf - V0lvf), CLAMP2));
        const float exp_rv = fast_exp2(fminf(lamr_l2e * (Vrvf - V0rvf), CLAMP2));
        const float ome = 1.0f - e;
        const float Plvf = e * Elvf * (Vlvf - Vdlvf) + ome * P0lvf * (exp_lv - 1.0f);
        const float Prvf = e * Ervf * (Vrvf - Vdrvf) + ome * P0rvf * (exp_rv - 1.0f);
        const float Plv = Plvf + Pperi;
        const float Prv = Prvf + Pperi;
        const float Pao = Eao * (Vao - Vdao);
        const float Pvc = Evc * (Vvc - Vdvc);
        const float Ppa = fmaf(Epa, Vpa - Vdpa, Pth);
        const float Ppu = fmaf(Epu, Vpu - Vdpu, Pth);
        const float Qsys = (Pao - Pvc) * inv_Rsys;
        const float Qpul = (Ppa - Ppu) * inv_Rpul;

        du[r * 10 + 0] = ((Ppu - Plv > 0.0f) || (Qmt > 0.0f)) ? (Ppu - Plv - Qmt * Rmt) * inv_Lmt : 0.0f;
        du[r * 10 + 1] = ((Plv - Pao > 0.0f) || (Qav > 0.0f)) ? (Plv - Pao - Qav * Rav) * inv_Lav : 0.0f;
        du[r * 10 + 2] = ((Pvc - Prv > 0.0f) || (Qtc > 0.0f)) ? (Pvc - Prv - Qtc * Rtc) * inv_Ltc : 0.0f;
        du[r * 10 + 3] = ((Prv - Ppa > 0.0f) || (Qpv > 0.0f)) ? (Prv - Ppa - Qpv * Rpv) * inv_Lpv : 0.0f;

        const float Qmt_c = fmaxf(Qmt, 0.0f);
        const float Qav_c = fmaxf(Qav, 0.0f);
        const float Qtc_c = fmaxf(Qtc, 0.0f);
        const float Qpv_c = fmaxf(Qpv, 0.0f);
        du[r * 10 + 4] = Qmt_c - Qav_c;
        du[r * 10 + 5] = Qav_c - Qsys;
        du[r * 10 + 6] = Qsys - Qtc_c;
        du[r * 10 + 7] = Qtc_c - Qpv_c;
        du[r * 10 + 8] = Qpv_c - Qpul;
        du[r * 10 + 9] = Qpul - Qmt_c;
    }

    float4* o4 = reinterpret_cast<float4*>(out + (size_t)g * (ROWS * 10));
#pragma unroll
    for (int i = 0; i < 10; ++i) o4[i] = reinterpret_cast<const float4*>(du)[i];
}

extern "C" void kernel_launch(void* const* d_in, const int* in_sizes, int n_in,
                              void* d_out, int out_size, void* d_ws, size_t ws_size,
                              hipStream_t stream) {
    const float* t  = (const float*)d_in[0];
    const float* u  = (const float*)d_in[1];
    const float* p  = (const float*)d_in[2];
    const float* W1 = (const float*)d_in[3];
    const float* b1 = (const float*)d_in[4];
    const float* W2 = (const float*)d_in[5];
    const float* b2 = (const float*)d_in[6];
    float* out = (float*)d_out;

    ode_kernel<<<NBLK, BLK, 0, stream>>>(t, u, p, W1, b1, W2, b2, out);
}